// Round 5
// baseline (1237.432 us; speedup 1.0000x reference)
//
#include <hip/hip_runtime.h>

// Elman RNN (relu), B=4096 T=4096 H=32, fp32.
// Mapping: 16-lane row = 1 batch; lane j holds hidden units j and j+16.
// h_new[j] = relu( sum_k h[k]*W_hh[j,k] + x*W_ih[j] + b_ih[j]+b_hh[j] )
//
// R4 post-mortem: v_fmac_f32_dpp issues at ~4.6 cyc (quarter rate) on gfx950
// — busy ~300 cyc/step across 3 different codegens = 60 DPP x 4.6 + misc.
// R5: XOR re-indexing  out[j] = sum_m W[j, j^m] * h[j^m]  with the transport
// done by ds_swizzle_b32 (xor mask, BitMode offset (m<<10)|0x1F) on the LDS
// pipe, overlapped with plain 2-cyc v_fmac_f32 on the VALU.
// Software pipeline: 6 masks issued ahead; staged s_waitcnt lgkmcnt (ds ops
// complete in order); 8 accumulator chains for fma-latency spacing.
// 1024 waves = 1 wave/SIMD; 64 plain fmac/step/wave = the FLOP floor.

#define HSZ 32

// dst = h value from lane (lane ^ m) within the 16-lane row (async, lgkmcnt)
#define SWZ(dst, src, off)                                   \
  asm volatile("ds_swizzle_b32 %0, %1 offset:" off           \
               : "=v"(dst) : "v"(src))

#define VFMAC(acc, a, b) \
  asm volatile("v_fmac_f32 %0, %1, %2" : "+v"(acc) : "v"(a), "v"(b))
#define VMUL(dst, a, b) \
  asm volatile("v_mul_f32 %0, %1, %2" : "=v"(dst) : "v"(a), "v"(b))

// chain-0 (masks 1..7) / chain-1 (masks 8..15) consume blocks
#define CONS0(m, tl, th)                                     \
  VFMAC(aA0, tl, wll[m]); VFMAC(aB0, th, wlh[m]);            \
  VFMAC(aC0, tl, whl[m]); VFMAC(aD0, th, whh[m])
#define CONS1(m, tl, th)                                     \
  VFMAC(aA1, tl, wll[m]); VFMAC(aB1, th, wlh[m]);            \
  VFMAC(aC1, tl, whl[m]); VFMAC(aD1, th, whh[m])

// One recurrence step. Issue-ahead depth 6 masks (12 ds ops <= 15 so
// lgkmcnt values stay encodable); each consume retires one pair (wait
// lgkmcnt(10) in steady state) and issues the pair 6 masks ahead.
#define RNN_STEP(xs)                                                        \
  do {                                                                      \
    float t1l,t1h,t2l,t2h,t3l,t3h,t4l,t4h,t5l,t5h,t6l,t6h,t7l,t7h;          \
    float t8l,t8h,t9l,t9h,t10l,t10h,t11l,t11h,t12l,t12h,t13l,t13h;          \
    float t14l,t14h,t15l,t15h;                                              \
    SWZ(t1l,h_lo,"0x041F"); SWZ(t1h,h_hi,"0x041F");                         \
    SWZ(t2l,h_lo,"0x081F"); SWZ(t2h,h_hi,"0x081F");                         \
    SWZ(t3l,h_lo,"0x0C1F"); SWZ(t3h,h_hi,"0x0C1F");                         \
    SWZ(t4l,h_lo,"0x101F"); SWZ(t4h,h_hi,"0x101F");                         \
    SWZ(t5l,h_lo,"0x141F"); SWZ(t5h,h_hi,"0x141F");                         \
    SWZ(t6l,h_lo,"0x181F"); SWZ(t6h,h_hi,"0x181F");                         \
    float aA0 = fmaf((xs), wih_lo, c_lo);                                   \
    float aC0 = fmaf((xs), wih_hi, c_hi);                                   \
    aA0 = fmaf(h_lo, wll[0], aA0);  /* m=0: k=jj, lane-local */             \
    aC0 = fmaf(h_lo, whl[0], aC0);                                          \
    float aB0 = h_hi * wlh[0];                                              \
    float aD0 = h_hi * whh[0];                                              \
    float aA1, aB1, aC1, aD1;                                               \
    asm volatile("s_waitcnt lgkmcnt(10)");                                  \
    CONS0(1, t1l, t1h);  SWZ(t7l,h_lo,"0x1C1F"); SWZ(t7h,h_hi,"0x1C1F");    \
    asm volatile("s_waitcnt lgkmcnt(10)");                                  \
    CONS0(2, t2l, t2h);  SWZ(t8l,h_lo,"0x201F"); SWZ(t8h,h_hi,"0x201F");    \
    asm volatile("s_waitcnt lgkmcnt(10)");                                  \
    CONS0(3, t3l, t3h);  SWZ(t9l,h_lo,"0x241F"); SWZ(t9h,h_hi,"0x241F");    \
    asm volatile("s_waitcnt lgkmcnt(10)");                                  \
    CONS0(4, t4l, t4h);  SWZ(t10l,h_lo,"0x281F"); SWZ(t10h,h_hi,"0x281F");  \
    asm volatile("s_waitcnt lgkmcnt(10)");                                  \
    CONS0(5, t5l, t5h);  SWZ(t11l,h_lo,"0x2C1F"); SWZ(t11h,h_hi,"0x2C1F");  \
    asm volatile("s_waitcnt lgkmcnt(10)");                                  \
    CONS0(6, t6l, t6h);  SWZ(t12l,h_lo,"0x301F"); SWZ(t12h,h_hi,"0x301F");  \
    asm volatile("s_waitcnt lgkmcnt(10)");                                  \
    CONS0(7, t7l, t7h);  SWZ(t13l,h_lo,"0x341F"); SWZ(t13h,h_hi,"0x341F");  \
    asm volatile("s_waitcnt lgkmcnt(10)");                                  \
    VMUL(aA1, t8l, wll[8]); VMUL(aB1, t8h, wlh[8]);                         \
    VMUL(aC1, t8l, whl[8]); VMUL(aD1, t8h, whh[8]);                         \
    SWZ(t14l,h_lo,"0x381F"); SWZ(t14h,h_hi,"0x381F");                       \
    asm volatile("s_waitcnt lgkmcnt(10)");                                  \
    CONS1(9, t9l, t9h);  SWZ(t15l,h_lo,"0x3C1F"); SWZ(t15h,h_hi,"0x3C1F");  \
    asm volatile("s_waitcnt lgkmcnt(10)");                                  \
    CONS1(10, t10l, t10h);                                                  \
    asm volatile("s_waitcnt lgkmcnt(8)");                                   \
    CONS1(11, t11l, t11h);                                                  \
    asm volatile("s_waitcnt lgkmcnt(6)");                                   \
    CONS1(12, t12l, t12h);                                                  \
    asm volatile("s_waitcnt lgkmcnt(4)");                                   \
    CONS1(13, t13l, t13h);                                                  \
    asm volatile("s_waitcnt lgkmcnt(2)");                                   \
    CONS1(14, t14l, t14h);                                                  \
    asm volatile("s_waitcnt lgkmcnt(0)");                                   \
    CONS1(15, t15l, t15h);                                                  \
    float slo = (aA0 + aB0) + (aA1 + aB1);                                  \
    float shi = (aC0 + aD0) + (aC1 + aD1);                                  \
    asm volatile("v_max_f32 %0, 0, %1\n\ts_nop 1" : "=v"(h_lo) : "v"(slo)); \
    asm volatile("v_max_f32 %0, 0, %1\n\ts_nop 1" : "=v"(h_hi) : "v"(shi)); \
  } while (0)

__global__ __attribute__((amdgpu_flat_work_group_size(256, 256),
                          amdgpu_waves_per_eu(1, 1)))
void rnn_reg_kernel(
    const float* __restrict__ x, const float* __restrict__ h_init,
    const float* __restrict__ W_ih, const float* __restrict__ W_hh,
    const float* __restrict__ b_ih, const float* __restrict__ b_hh,
    const float* __restrict__ W_reg, const float* __restrict__ b_reg,
    float* __restrict__ out, int T) {
  const int jj  = threadIdx.x & 15;   // hidden-lane within row
  const int row = threadIdx.x >> 4;   // 0..15 rows per block
  const int b   = blockIdx.x * 16 + row;

  // XOR-gathered weights: with swizzle mask m, lane j receives h[j^m],
  // so the coefficient is W_hh[out_row, in_col = j^m].
  float wll[16], wlh[16], whl[16], whh[16];
#pragma unroll
  for (int m = 0; m < 16; ++m) {
    int k = jj ^ m;
    wll[m] = W_hh[jj * HSZ + k];              // out j,    in k
    wlh[m] = W_hh[jj * HSZ + 16 + k];         // out j,    in 16+k
    whl[m] = W_hh[(jj + 16) * HSZ + k];       // out j+16, in k
    whh[m] = W_hh[(jj + 16) * HSZ + 16 + k];  // out j+16, in 16+k
  }
  const float wih_lo = W_ih[jj];
  const float wih_hi = W_ih[jj + 16];
  const float c_lo = b_ih[jj] + b_hh[jj];
  const float c_hi = b_ih[jj + 16] + b_hh[jj + 16];

  float h_lo = h_init[b * HSZ + jj];
  float h_hi = h_init[b * HSZ + jj + 16];

  // x feed: all 16 lanes of a row load the same float4 (HW merges the
  // same-address lanes). 4-deep rotating pipeline = 16-step prefetch
  // distance covering cold-HBM latency (~900 cyc).
  const float4* xv = (const float4*)(x + (size_t)b * (size_t)T);
  const int last = T / 4 - 1;
  float4 x0 = xv[0], x1 = xv[1], x2 = xv[2], x3 = xv[3];

#pragma unroll 1
  for (int t = 0; t < T; t += 16) {
    const int base = t >> 2;
    int i0 = base + 4; i0 = i0 > last ? last : i0;
    int i1 = base + 5; i1 = i1 > last ? last : i1;
    int i2 = base + 6; i2 = i2 > last ? last : i2;
    int i3 = base + 7; i3 = i3 > last ? last : i3;
    float4 n0 = xv[i0];
    RNN_STEP(x0.x); RNN_STEP(x0.y); RNN_STEP(x0.z); RNN_STEP(x0.w);
    float4 n1 = xv[i1];
    RNN_STEP(x1.x); RNN_STEP(x1.y); RNN_STEP(x1.z); RNN_STEP(x1.w);
    float4 n2 = xv[i2];
    RNN_STEP(x2.x); RNN_STEP(x2.y); RNN_STEP(x2.z); RNN_STEP(x2.w);
    float4 n3 = xv[i3];
    RNN_STEP(x3.x); RNN_STEP(x3.y); RNN_STEP(x3.z); RNN_STEP(x3.w);
    x0 = n0; x1 = n1; x2 = n2; x3 = n3;
  }

  // out[b] = sum_j h[j]*W_reg[j] + b_reg  (reduce across the 16-lane row)
  const float wr_lo = W_reg[jj];
  const float wr_hi = W_reg[jj + 16];
  float v = fmaf(h_lo, wr_lo, h_hi * wr_hi);
  v += __shfl_xor(v, 1, 16);
  v += __shfl_xor(v, 2, 16);
  v += __shfl_xor(v, 4, 16);
  v += __shfl_xor(v, 8, 16);
  if (jj == 0) out[b] = v + b_reg[0];
}

extern "C" void kernel_launch(void* const* d_in, const int* in_sizes, int n_in,
                              void* d_out, int out_size, void* d_ws, size_t ws_size,
                              hipStream_t stream) {
  const float* x      = (const float*)d_in[0];
  const float* h_init = (const float*)d_in[1];
  const float* W_ih   = (const float*)d_in[2];
  const float* W_hh   = (const float*)d_in[3];
  const float* b_ih   = (const float*)d_in[4];
  const float* b_hh   = (const float*)d_in[5];
  const float* W_reg  = (const float*)d_in[6];
  const float* b_reg  = (const float*)d_in[7];
  float* out = (float*)d_out;

  const int B = in_sizes[1] / HSZ;          // 4096
  const int T = in_sizes[0] / B;            // 4096
  const int grid = B / 16;                  // 16 batches (rows) per 256-thr block

  rnn_reg_kernel<<<dim3(grid), dim3(256), 0, stream>>>(
      x, h_init, W_ih, W_hh, b_ih, b_hh, W_reg, b_reg, out, T);
}

// Round 6
// 636.537 us; speedup vs baseline: 1.9440x; 1.9440x over previous
//
#include <hip/hip_runtime.h>

// Elman RNN (relu), B=4096 T=4096 H=32, fp32.
// h_new[j] = relu( sum_k h[k]*W_hh[j,k] + x*W_ih[j] + b_ih[j]+b_hh[j] )
//
// HW model (R3/R4/R5 measured): single-wave issue cadence ~5.2 cyc/instr on
// gfx950, independent of instr type (DPP fmac, plain fmac, DS, waitcnt all
// cost the same sequencer slot). Serial recurrence => minimize instructions
// per step on ONE wave's critical path; extra waves don't shorten it.
//
// Mapping: 32 lanes per batch (2 batches/wave, wave halves are independent
// 32-lane swizzle groups). Lane q in [0,32) owns out[q] and holds h[q].
//   - same-row k (15 rotations): fused v_fmac_f32_dpp row_ror:m
//   - other-row k (16 values): ONE ds_swizzle_b32 xor16 (0x401F) per step,
//     latency hidden behind the 16 same-row fmacs, then 15 more row_ror
//     fmacs on the swizzled register.
// => 32 fmac + 1 swizzle + ~5 overhead ≈ 38 instr/step (vs R4's ~80).
// 512 blocks x 256 thr = 2048 waves = 2 waves/SIMD.

#define HSZ 32

// acc += row_ror<m>(src) * w   (fused DPP transport + MAC)
#define FMAC_DPP(acc, src, w, mlit)                                           \
  asm volatile(                                                               \
      "v_fmac_f32_dpp %0, %1, %2 row_ror:" mlit " row_mask:0xf bank_mask:0xf" \
      : "+v"(acc)                                                             \
      : "v"(src), "v"(w))

#define FMAC(acc, src, w) \
  asm volatile("v_fmac_f32 %0, %1, %2" : "+v"(acc) : "v"(src), "v"(w))

// dst[q] = src[q ^ 16] within each 32-lane group (BitMode xor=16)
#define SWZ16(dst, src) \
  asm volatile("ds_swizzle_b32 %0, %1 offset:0x401F" : "=v"(dst) : "v"(src))

// One recurrence step.
// Hazard notes: relu (VALU) -> first DPP read of h has >=2 instrs in between
// (swizzle + plain FMAC m=0) => no nop needed. DS-return -> DPP read of oh:
// s_nop 1 after the lgkmcnt wait as insurance (costs one issue slot).
#define RNN_STEP(xs)                                                    \
  do {                                                                  \
    float oh;                                                           \
    SWZ16(oh, h);                       /* issue early: latency hides */\
    float acc = fmaf((xs), wih, c);                                     \
    FMAC(acc, h, wm[0]);                                                \
    FMAC_DPP(acc, h, wm[1], "1");   FMAC_DPP(acc, h, wm[2], "2");       \
    FMAC_DPP(acc, h, wm[3], "3");   FMAC_DPP(acc, h, wm[4], "4");       \
    FMAC_DPP(acc, h, wm[5], "5");   FMAC_DPP(acc, h, wm[6], "6");       \
    FMAC_DPP(acc, h, wm[7], "7");   FMAC_DPP(acc, h, wm[8], "8");       \
    FMAC_DPP(acc, h, wm[9], "9");   FMAC_DPP(acc, h, wm[10], "10");     \
    FMAC_DPP(acc, h, wm[11], "11"); FMAC_DPP(acc, h, wm[12], "12");     \
    FMAC_DPP(acc, h, wm[13], "13"); FMAC_DPP(acc, h, wm[14], "14");     \
    FMAC_DPP(acc, h, wm[15], "15");                                     \
    asm volatile("s_waitcnt lgkmcnt(0)\n\ts_nop 1");                    \
    FMAC(acc, oh, wo[0]);                                               \
    FMAC_DPP(acc, oh, wo[1], "1");   FMAC_DPP(acc, oh, wo[2], "2");     \
    FMAC_DPP(acc, oh, wo[3], "3");   FMAC_DPP(acc, oh, wo[4], "4");     \
    FMAC_DPP(acc, oh, wo[5], "5");   FMAC_DPP(acc, oh, wo[6], "6");     \
    FMAC_DPP(acc, oh, wo[7], "7");   FMAC_DPP(acc, oh, wo[8], "8");     \
    FMAC_DPP(acc, oh, wo[9], "9");   FMAC_DPP(acc, oh, wo[10], "10");   \
    FMAC_DPP(acc, oh, wo[11], "11"); FMAC_DPP(acc, oh, wo[12], "12");   \
    FMAC_DPP(acc, oh, wo[13], "13"); FMAC_DPP(acc, oh, wo[14], "14");   \
    FMAC_DPP(acc, oh, wo[15], "15");                                    \
    asm volatile("v_max_f32 %0, 0, %1" : "=v"(h) : "v"(acc));           \
  } while (0)

__global__ __launch_bounds__(256) void rnn_reg_kernel(
    const float* __restrict__ x, const float* __restrict__ h_init,
    const float* __restrict__ W_ih, const float* __restrict__ W_hh,
    const float* __restrict__ b_ih, const float* __restrict__ b_hh,
    const float* __restrict__ W_reg, const float* __restrict__ b_reg,
    float* __restrict__ out, int T) {
  const int q = threadIdx.x & 31;                  // hidden unit owned
  const int b = blockIdx.x * 8 + (threadIdx.x >> 5);  // batch (8 per block)

  // Same-row coefficients: row_ror:m delivers h[(q&16) | ((q-m)&15)].
  // Other-row: swizzle xor16 gives oh[q]=h[q^16]; row_ror:m on oh delivers
  // h[ ((q^16)&16) | ((q-m)&15) ].
  float wm[16], wo[16];
#pragma unroll
  for (int m = 0; m < 16; ++m) {
    int klo = (q - m) & 15;
    wm[m] = W_hh[q * HSZ + ((q & 16) | klo)];
    wo[m] = W_hh[q * HSZ + (((q ^ 16) & 16) | klo)];
  }
  const float wih = W_ih[q];
  const float c   = b_ih[q] + b_hh[q];

  float h = h_init[b * HSZ + q];

  // x feed: all 32 lanes of a group load the same float4 (HW merges).
  // 2-deep rotating pipeline = 8-step prefetch (~1700 cyc) >> HBM latency.
  const float4* xv = (const float4*)(x + (size_t)b * (size_t)T);
  const int last = T / 4 - 1;
  float4 x0 = xv[0], x1 = xv[1];

#pragma unroll 1
  for (int t = 0; t < T; t += 8) {
    const int base = t >> 2;
    int i0 = base + 2; i0 = i0 > last ? last : i0;
    int i1 = base + 3; i1 = i1 > last ? last : i1;
    float4 n0 = xv[i0];
    RNN_STEP(x0.x); RNN_STEP(x0.y); RNN_STEP(x0.z); RNN_STEP(x0.w);
    float4 n1 = xv[i1];
    RNN_STEP(x1.x); RNN_STEP(x1.y); RNN_STEP(x1.z); RNN_STEP(x1.w);
    x0 = n0; x1 = n1;
  }

  // out[b] = sum_q h[q]*W_reg[q] + b_reg  (reduce across the 32-lane group)
  float v = h * W_reg[q];
  v += __shfl_xor(v, 1, 32);
  v += __shfl_xor(v, 2, 32);
  v += __shfl_xor(v, 4, 32);
  v += __shfl_xor(v, 8, 32);
  v += __shfl_xor(v, 16, 32);
  if (q == 0) out[b] = v + b_reg[0];
}

extern "C" void kernel_launch(void* const* d_in, const int* in_sizes, int n_in,
                              void* d_out, int out_size, void* d_ws, size_t ws_size,
                              hipStream_t stream) {
  const float* x      = (const float*)d_in[0];
  const float* h_init = (const float*)d_in[1];
  const float* W_ih   = (const float*)d_in[2];
  const float* W_hh   = (const float*)d_in[3];
  const float* b_ih   = (const float*)d_in[4];
  const float* b_hh   = (const float*)d_in[5];
  const float* W_reg  = (const float*)d_in[6];
  const float* b_reg  = (const float*)d_in[7];
  float* out = (float*)d_out;

  const int B = in_sizes[1] / HSZ;          // 4096
  const int T = in_sizes[0] / B;            // 4096
  const int grid = B / 8;                   // 8 batches per 256-thr block

  rnn_reg_kernel<<<dim3(grid), dim3(256), 0, stream>>>(
      x, h_init, W_ih, W_hh, b_ih, b_hh, W_reg, b_reg, out, T);
}